// Round 14
// baseline (73.071 us; speedup 1.0000x reference)
//
#include <hip/hip_runtime.h>
#include <math.h>

typedef _Float16 half8 __attribute__((ext_vector_type(8)));
typedef float    f32x4 __attribute__((ext_vector_type(4)));

#define TOKENS  32768
#define HIDDEN  2048
#define EXPERTS 64
#define TOPK    8
#define BKW     128                // k per staged window
#define NWIN    (HIDDEN / BKW)     // 16
#define WROW    128                // W LDS row stride in halves (256 B, linear)
#define WBUFB   32768              // bytes per W buffer (hi 16KB + lo 16KB)

#define GLB(p) ((const __attribute__((address_space(1))) char*)(p))
#define LDS(p) ((__attribute__((address_space(3))) char*)(p))

// ---------------------------------------------------------------------------
// Kernel 1: split W fp32 -> fp16 hi/lo, packed PRE-SWIZZLED for gload_lds:
// chunk id = (win*64 + er)*16 + c  holds  W[er][win*128 + (c^(er&7))*8 .. +8).
// Router stages it linearly into LDS [er][256B] via global_load_lds; B-frag
// reads apply the same XOR -> bank-conflict-free (m201 both-sides rule).
// ---------------------------------------------------------------------------
__global__ void wsplit_pack(const float* __restrict__ W,
                            _Float16* __restrict__ whp, _Float16* __restrict__ wlp) {
    int id = blockIdx.x * 256 + threadIdx.x;    // 0..16383 chunks of 8 halves
    int win = id >> 10;
    int er  = (id >> 4) & 63;
    int c   = id & 15;
    int k0  = win * BKW + ((c ^ (er & 7)) << 3);
    const float* src = W + (size_t)er * HIDDEN + k0;
    float4 v0 = *(const float4*)(src);
    float4 v1 = *(const float4*)(src + 4);
    float f[8] = {v0.x, v0.y, v0.z, v0.w, v1.x, v1.y, v1.z, v1.w};
    half8 hi, lo;
    #pragma unroll
    for (int j = 0; j < 8; ++j) {
        _Float16 h = (_Float16)f[j];
        hi[j] = h;
        lo[j] = (_Float16)(f[j] - (float)h);
    }
    *(half8*)(whp + (size_t)id * 8) = hi;
    *(half8*)(wlp + (size_t)id * 8) = lo;
}

// ---------------------------------------------------------------------------
// Kernel 2: MFMA router, fp16x3 split (hi*hi + hi*lo + lo*hi, fp32 acc).
// r13 vs r12: BKW=128 so one window's compute (~1200cyc) exceeds HBM latency
// -- the __syncthreads vmcnt(0) drain at window end waits on nothing; and W
// staged by global_load_lds (no VGPR round-trip, no ds_writes). A direct
// global->reg in MFMA frag layout (verified r10/r12), 2 static window sets.
// Block = 256 thr = 4 waves = 64 tokens x 64 experts x full K; 1 barrier/win.
// ---------------------------------------------------------------------------
__global__ __launch_bounds__(256, 1)
void router_gl(const float* __restrict__ A,
               const _Float16* __restrict__ WhP,
               const _Float16* __restrict__ WlP,
               const float* __restrict__ bias,
               float* __restrict__ out) {
    __shared__ __align__(1024) char smem[2 * WBUFB];   // 64 KB: 2 x (Whi|Wlo)
    const int tid = threadIdx.x;
    const int wv  = tid >> 6;          // wave = 16-token slab
    const int l   = tid & 63;
    const int g   = blockIdx.x;

    // A direct-load base: lane row (l&15), k-chunk (l>>4)*8
    const float* pa = A + ((size_t)(g * 64 + wv * 16 + (l & 15))) * HIDDEN + ((l >> 4) << 3);

    f32x4 acc[4];
    #pragma unroll
    for (int n = 0; n < 4; ++n) acc[n] = (f32x4){0.f, 0.f, 0.f, 0.f};

    // A register queue: two static window-sets, 8 float4 each (rule #20)
    float4 qA0, qA1, qA2, qA3, qA4, qA5, qA6, qA7;
    float4 qB0, qB1, qB2, qB3, qB4, qB5, qB6, qB7;

    #define LOADA(S, win) do {                                               \
        const float* p_ = pa + (win) * BKW;                                  \
        q##S##0 = *(const float4*)(p_);        q##S##1 = *(const float4*)(p_ + 4);    \
        q##S##2 = *(const float4*)(p_ + 32);   q##S##3 = *(const float4*)(p_ + 36);   \
        q##S##4 = *(const float4*)(p_ + 64);   q##S##5 = *(const float4*)(p_ + 68);   \
        q##S##6 = *(const float4*)(p_ + 96);   q##S##7 = *(const float4*)(p_ + 100);  \
    } while (0)

    // W stage via global_load_lds: wave wv stages rows wv*16..+15 (4KB hi + 4KB lo)
    #define GLOADW(win, bufoff) do {                                         \
        _Pragma("unroll")                                                    \
        for (int i_ = 0; i_ < 4; ++i_) {                                     \
            const size_t go_ = (size_t)(win) * 16384 + (wv * 16 + i_ * 4) * 256 + l * 16; \
            char* dh_ = smem + (bufoff) + (wv * 16 + i_ * 4) * 256;          \
            char* dl_ = dh_ + 16384;                                         \
            __builtin_amdgcn_global_load_lds(GLB((const char*)WhP + go_), LDS(dh_), 16, 0, 0); \
            __builtin_amdgcn_global_load_lds(GLB((const char*)WlP + go_), LDS(dl_), 16, 0, 0); \
        }                                                                    \
    } while (0)

    #define CVT8(HI, LO, V0, V1) do {                                        \
        float f_[8] = {(V0).x, (V0).y, (V0).z, (V0).w,                       \
                       (V1).x, (V1).y, (V1).z, (V1).w};                      \
        _Pragma("unroll")                                                    \
        for (int j_ = 0; j_ < 8; ++j_) {                                     \
            _Float16 h_ = (_Float16)f_[j_];                                  \
            (HI)[j_] = h_;                                                   \
            (LO)[j_] = (_Float16)(f_[j_] - (float)h_);                       \
        }                                                                    \
    } while (0)

    // one k-tile (32 k): cvt A pair, read swizzled B frags, 12 MFMAs
    #define KTILE(bufoff, KT, V0, V1) do {                                   \
        half8 ahi_, alo_;                                                    \
        CVT8(ahi_, alo_, V0, V1);                                            \
        const _Float16* wh_ = (const _Float16*)(smem + (bufoff));            \
        const _Float16* wl_ = (const _Float16*)(smem + (bufoff) + 16384);    \
        _Pragma("unroll")                                                    \
        for (int n = 0; n < 4; ++n) {                                        \
            const int er_ = n * 16 + (l & 15);                               \
            const int cp_ = (((KT) * 4 + (l >> 4)) ^ (er_ & 7)) << 3;        \
            half8 bh = *(const half8*)(wh_ + er_ * WROW + cp_);              \
            half8 bl = *(const half8*)(wl_ + er_ * WROW + cp_);              \
            acc[n] = __builtin_amdgcn_mfma_f32_16x16x32_f16(ahi_, bh, acc[n], 0, 0, 0); \
            acc[n] = __builtin_amdgcn_mfma_f32_16x16x32_f16(ahi_, bl, acc[n], 0, 0, 0); \
            acc[n] = __builtin_amdgcn_mfma_f32_16x16x32_f16(alo_, bh, acc[n], 0, 0, 0); \
        }                                                                    \
    } while (0)

    #define COMPUTE(bufoff, S) do {                                          \
        KTILE(bufoff, 0, q##S##0, q##S##1);                                  \
        KTILE(bufoff, 1, q##S##2, q##S##3);                                  \
        KTILE(bufoff, 2, q##S##4, q##S##5);                                  \
        KTILE(bufoff, 3, q##S##6, q##S##7);                                  \
    } while (0)

    // ---- prologue: window 0 (W->buf0, A->set A); barrier drains both ----
    GLOADW(0, 0);
    LOADA(A, 0);
    __syncthreads();

    // ---- main loop: 1 barrier/window; issue-at-start, consume-next-window ----
    #pragma unroll 1
    for (int s = 0; s < NWIN; s += 2) {
        GLOADW(s + 1, WBUFB);                    // W s+1 -> buf1 (always: s+1<=15)
        LOADA(B, s + 1);                         // A s+1 -> set B
        COMPUTE(0, A);                           // window s from buf0 / set A
        __syncthreads();                         // drains: W s+1, A s+1 (both ~1 window old)

        if (s + 2 < NWIN) {
            GLOADW(s + 2, 0);                    // W s+2 -> buf0
            LOADA(A, s + 2);                     // A s+2 -> set A
        }
        COMPUTE(WBUFB, B);                       // window s+1 from buf1 / set B
        __syncthreads();
    }
    #undef LOADA
    #undef GLOADW
    #undef CVT8
    #undef KTILE
    #undef COMPUTE

    // ---- epilogue: logits (+bias) to LDS, top-8 + softmax + scatter ----
    float* lg = (float*)smem;                  // [64 tok][68]
    float* sc = (float*)smem + 64 * 68;        // [64 tok][65]

    // D layout (verified r8): token row = (l>>4)*4+q, expert col = n*16+(l&15)
    #pragma unroll
    for (int n = 0; n < 4; ++n) {
        float b = bias[n * 16 + (l & 15)];
        #pragma unroll
        for (int q = 0; q < 4; ++q) {
            int trow = wv * 16 + (l >> 4) * 4 + q;
            lg[trow * 68 + n * 16 + (l & 15)] = acc[n][q] + b;
        }
    }
    for (int i = tid; i < 64 * 65; i += 256) sc[i] = 0.f;
    __syncthreads();

    if (tid < 64) {
        const int t = tid;
        float v[64];
        #pragma unroll
        for (int e = 0; e < 64; ++e) v[e] = lg[t * 68 + e];

        float tvals[TOPK]; int tix[TOPK]; float probs[TOPK];
        unsigned long long chosen = 0ull;
        #pragma unroll
        for (int j = 0; j < TOPK; ++j) {
            float best = -INFINITY; int bi = 0;
            #pragma unroll
            for (int e = 0; e < 64; ++e) {
                bool ok = ((chosen >> e) & 1ull) == 0ull;
                if (ok && v[e] > best) { best = v[e]; bi = e; }  // strict >: lowest idx on tie
            }
            chosen |= (1ull << bi);
            tvals[j] = best; tix[j] = bi;
        }
        float m = tvals[0];
        float ssum = 0.f;
        #pragma unroll
        for (int j = 0; j < TOPK; ++j) { probs[j] = __expf(tvals[j] - m); ssum += probs[j]; }
        float inv = 1.f / ssum;
        #pragma unroll
        for (int j = 0; j < TOPK; ++j) probs[j] *= inv;

        #pragma unroll
        for (int j = 0; j < TOPK; ++j) sc[t * 65 + tix[j]] = probs[j];

        float* oidx = out + (size_t)TOKENS * EXPERTS;
        const int token = g * 64 + t;
        #pragma unroll
        for (int j = 0; j < TOPK; ++j) oidx[(size_t)token * TOPK + j] = (float)tix[j];
    }
    __syncthreads();

    // ---- coalesced score write: 64 tokens x 64 experts = 1024 float4 ----
    float* oscore = out + (size_t)g * 4096;
    #pragma unroll
    for (int p = 0; p < 4; ++p) {
        int fi  = tid + 256 * p;               // float4 index 0..1023
        int tok = fi >> 4;
        int es  = (fi & 15) * 4;
        float4 vv;
        vv.x = sc[tok * 65 + es + 0];
        vv.y = sc[tok * 65 + es + 1];
        vv.z = sc[tok * 65 + es + 2];
        vv.w = sc[tok * 65 + es + 3];
        *(float4*)(oscore + (size_t)fi * 4) = vv;
    }
}

extern "C" void kernel_launch(void* const* d_in, const int* in_sizes, int n_in,
                              void* d_out, int out_size, void* d_ws, size_t ws_size,
                              hipStream_t stream) {
    const float* A    = (const float*)d_in[0];   // [32768, 2048] fp32
    const float* W    = (const float*)d_in[1];   // [64, 2048] fp32
    const float* bias = (const float*)d_in[2];   // [64] fp32
    float* out = (float*)d_out;                  // scores (32768*64) ++ idx (32768*8)

    _Float16* whp = (_Float16*)d_ws;             // 256 KB packed+swizzled hi
    _Float16* wlp = whp + EXPERTS * HIDDEN;      // 256 KB packed+swizzled lo

    wsplit_pack<<<64, 256, 0, stream>>>(W, whp, wlp);
    router_gl<<<TOKENS / 64, 256, 0, stream>>>(A, whp, wlp, bias, out);
}